// Round 9
// baseline (257.896 us; speedup 1.0000x reference)
//
#include <hip/hip_runtime.h>

typedef unsigned short u16;
typedef __attribute__((ext_vector_type(8))) short bf16x8;
typedef __attribute__((ext_vector_type(4))) float f32x4;

#define MFMA16(a,b,c) __builtin_amdgcn_mfma_f32_16x16x32_bf16((a),(b),(c),0,0,0)

__device__ __forceinline__ float b2f(u16 u){
  unsigned v = ((unsigned)u) << 16; float f;
  __builtin_memcpy(&f, &v, 4); return f;
}
__device__ __forceinline__ u16 f2b(float f){
  unsigned v; __builtin_memcpy(&v, &f, 4);
  v += 0x7FFFu + ((v >> 16) & 1u);
  return (u16)(v >> 16);
}
__device__ __forceinline__ float scrub(float v, float lim){
  return fminf(fmaxf(v, -lim), lim);   // NaN-filtering clamp
}
__device__ __forceinline__ void gload16(const void* g, void* l){
  __builtin_amdgcn_global_load_lds(
      (const __attribute__((address_space(1))) unsigned int*)g,
      (__attribute__((address_space(3))) unsigned int*)l, 16, 0, 0);
}

// ---- convert+transpose tile helper: dst[c][r] = bf16(src[r][c]) ----
__device__ __forceinline__ void cvtT_tile(float (*tile)[33],
    u16* __restrict__ dst, const float* __restrict__ src,
    int rows, int cols, int bx, int by, int tid){
  int n0 = bx * 32, r0 = by * 32;
  int tx = tid & 31, ty = tid >> 5;
#pragma unroll
  for (int i = 0; i < 4; i++)
    tile[ty + i * 8][tx] = src[(size_t)(r0 + ty + i * 8) * cols + n0 + tx];
  __syncthreads();
#pragma unroll
  for (int i = 0; i < 4; i++)
    dst[(size_t)(n0 + ty + i * 8) * rows + r0 + tx] = f2b(tile[tx][ty + i * 8]);
}

// ---- prep1: x -> bf16 (5760 blocks) + WqT (11520 blocks) ----
__global__ __launch_bounds__(256) void k_prep1(
    u16* __restrict__ xb, const float* __restrict__ x,
    u16* __restrict__ wqT, const float* __restrict__ Wq){
  __shared__ float tile[32][33];
  int b = blockIdx.x, tid = threadIdx.x;
  if (b < 5760){
    int i = b * 256 + tid;
    float4 v = ((const float4*)x)[i];
    u16 o[4] = { f2b(v.x), f2b(v.y), f2b(v.z), f2b(v.w) };
    *(uint2*)&xb[(size_t)i * 4] = *(const uint2*)o;
    return;
  }
  b -= 5760;
  cvtT_tile(tile, wqT, Wq, 2880, 4096, b % 128, b / 128, tid);
}

// ---- prep2: WkT + WvT (1440 each) ----
__global__ __launch_bounds__(256) void k_prep2(
    u16* __restrict__ wkvT, const float* __restrict__ Wk,
    const float* __restrict__ Wv){
  __shared__ float tile[32][33];
  int b = blockIdx.x, tid = threadIdx.x;
  if (b < 1440){ cvtT_tile(tile, wkvT, Wk, 2880, 512, b % 16, b / 16, tid); return; }
  b -= 1440;
  cvtT_tile(tile, wkvT + (size_t)512 * 2880, Wv, 2880, 512, b % 16, b / 16, tid);
}

// ---- prep3: WoT (11520 blocks) ----
__global__ __launch_bounds__(256) void k_prep3(
    u16* __restrict__ woT, const float* __restrict__ Wo){
  __shared__ float tile[32][33];
  int b = blockIdx.x, tid = threadIdx.x;
  cvtT_tile(tile, woT, Wo, 4096, 2880, b % 90, b / 90, tid);
}

// ======== 4-wave GEMM: BM=256, BN=128, BK=64, 256 thr, per-wave 128x64 ========
// m201 per-wave geometry (0.375 LDS reads/MFMA). 3-buffer LDS ring (144KB):
// reads buf t, stages buf t+2 -> ONE barrier + counted vmcnt(12) per K-tile.
// 16B k-XOR swizzle (verified 0 conflicts). B rows >=4096 come from BT2
// (fused KV projection); bias/rope selected per column.
template<int F32OUT, int ROPE>
__global__ __launch_bounds__(256, 1) void k_g4w(
    const u16* __restrict__ A, const u16* __restrict__ BT, const u16* __restrict__ BT2,
    const float* __restrict__ b0, const float* __restrict__ b1, const float* __restrict__ b2,
    void* __restrict__ C, const int* __restrict__ pos, int M, int N, int K, int ldc){
  __shared__ u16 lds[3][24576];   // per buf: A[256][64] @0, B[128][64] @16384

  const int tid = threadIdx.x;
  const int w = tid >> 6, l = tid & 63;
  const int wm = w >> 1, wn = w & 1;          // 2 x 2 waves, per-wave 128x64
  const int lr = l & 15, lh = l >> 4;
  const int bid = blockIdx.x;
  const int mt = bid & 7, nt = bid >> 3;      // M = 2048 -> 8 mt
  const int m0 = mt << 8, n0 = nt << 7;

  const int srow = tid >> 3;                  // 0..31
  const int skc  = (tid & 7) << 3;            // 0,8,..,56 (elements)
  const int ssw  = (srow & 7) << 3;           // stage-source k swizzle (16B gran)
  const int rsw  = (lr & 7) << 3;             // read-side k swizzle

  f32x4 acc[8][4];
#pragma unroll
  for (int mm = 0; mm < 8; mm++)
#pragma unroll
    for (int nn = 0; nn < 4; nn++){ acc[mm][nn][0]=0.f; acc[mm][nn][1]=0.f; acc[mm][nn][2]=0.f; acc[mm][nn][3]=0.f; }

#define STAGE_A(b, kt, c) \
  gload16(&A[(size_t)(m0 + (c)*32 + srow) * K + (kt) + (skc ^ ssw)], \
          (void*)&lds[b][((c)*32 + srow) * 64 + skc])
#define STAGE_B(b, kt, c) { \
  int _r = n0 + (c)*32 + srow; if (_r > N - 1) _r = N - 1; \
  const u16* _bt = BT; \
  if (_r >= 4096){ _bt = BT2; _r -= 4096; } \
  gload16(&_bt[(size_t)_r * K + (kt) + (skc ^ ssw)], \
          (void*)&lds[b][16384 + ((c)*32 + srow) * 64 + skc]); }

#define RD_A(dst, As, mm, kk) dst = *(const bf16x8*)&(As)[((wm<<7) + ((mm)<<4) + lr) * 64 + ((((kk)<<5) + (lh<<3)) ^ rsw)]
#define RD_B(dst, Bs, nn, kk) dst = *(const bf16x8*)&(Bs)[((wn<<6) + ((nn)<<4) + lr) * 64 + ((((kk)<<5) + (lh<<3)) ^ rsw)]

  const int NT = K >> 6;
  // prologue: stage tiles 0,1 into bufs 0,1 (12 loads each)
#pragma unroll
  for (int tt = 0; tt < 2; ++tt){
    int kt = tt << 6;
#pragma unroll
    for (int c = 0; c < 8; ++c) STAGE_A(tt, kt, c);
#pragma unroll
    for (int c = 0; c < 4; ++c) STAGE_B(tt, kt, c);
  }
  asm volatile("s_waitcnt vmcnt(12)" ::: "memory");   // tile 0 complete
  __builtin_amdgcn_s_barrier();

  int cb = 0;
  for (int t = 0; t < NT; ++t){
    const u16* As = &lds[cb][0];
    const u16* Bs = &lds[cb][16384];
    int sb = cb + 2; if (sb >= 3) sb -= 3;
    const int kt2 = (t + 2) << 6;
    const bool ds = (t + 2) < NT;

    bf16x8 bf[4][2];
#pragma unroll
    for (int nn = 0; nn < 4; nn++){ RD_B(bf[nn][0], Bs, nn, 0); RD_B(bf[nn][1], Bs, nn, 1); }

#define MGROUP(mm) { \
    bf16x8 a0, a1; \
    RD_A(a0, As, mm, 0); RD_A(a1, As, mm, 1); \
    if (ds) STAGE_A(sb, kt2, mm); \
    if (ds && (mm) < 4) STAGE_B(sb, kt2, mm); \
    __builtin_amdgcn_s_setprio(1); \
    acc[mm][0]=MFMA16(a0,bf[0][0],acc[mm][0]); \
    acc[mm][1]=MFMA16(a0,bf[1][0],acc[mm][1]); \
    acc[mm][2]=MFMA16(a0,bf[2][0],acc[mm][2]); \
    acc[mm][3]=MFMA16(a0,bf[3][0],acc[mm][3]); \
    acc[mm][0]=MFMA16(a1,bf[0][1],acc[mm][0]); \
    acc[mm][1]=MFMA16(a1,bf[1][1],acc[mm][1]); \
    acc[mm][2]=MFMA16(a1,bf[2][1],acc[mm][2]); \
    acc[mm][3]=MFMA16(a1,bf[3][1],acc[mm][3]); \
    __builtin_amdgcn_s_setprio(0); }

    MGROUP(0) MGROUP(1) MGROUP(2) MGROUP(3)
    MGROUP(4) MGROUP(5) MGROUP(6) MGROUP(7)
#undef MGROUP

    // single sync point per K-tile: own t+1 loads drained, then block barrier
    if (ds) asm volatile("s_waitcnt vmcnt(12)" ::: "memory");
    else    asm volatile("s_waitcnt vmcnt(0)" ::: "memory");
    __builtin_amdgcn_s_barrier();

    cb += 1; if (cb >= 3) cb -= 3;
  }

  // ---- epilogue ----
#pragma unroll
  for (int mm = 0; mm < 8; mm++){
    int grow = m0 + (wm << 7) + (mm << 4) + (lh << 2);
#pragma unroll
    for (int nn = 0; nn < 4; nn++){
      int gcol = n0 + (wn << 6) + (nn << 4) + lr;
      if (gcol < N){
        float bs = (gcol < 4096) ? b0[gcol] : ((gcol < 4608) ? b1[gcol - 4096] : b2[gcol - 4608]);
        if (ROPE && gcol < 4608){
          int ii = (gcol & 63) >> 1;
          float inv = exp2f(-0.53733146f * (float)ii);
          float sgn = (lr & 1) ? 1.f : -1.f;
#pragma unroll
          for (int r = 0; r < 4; r++){
            float v = acc[mm][nn][r] + bs;
            float ang = (float)pos[grow + r] * 0.03125f * inv;
            float s, c; __sincosf(ang, &s, &c);
            float p = __shfl_xor(v, 1);
            v = v * c + p * sgn * s;
            ((u16*)C)[(size_t)(grow + r) * ldc + gcol] = f2b(scrub(v, 1e9f));
          }
        } else {
#pragma unroll
          for (int r = 0; r < 4; r++){
            float v = scrub(acc[mm][nn][r] + bs, 1e9f);
            size_t off = (size_t)(grow + r) * ldc + gcol;
            if (F32OUT) ((float*)C)[off] = v;
            else        ((u16*)C)[off]   = f2b(v);
          }
        }
      }
    }
  }
#undef STAGE_A
#undef STAGE_B
#undef RD_A
#undef RD_B
}

// ---------------- attention (unchanged, verified) ----------------
__global__ __launch_bounds__(256) void k_attn(
    const u16* __restrict__ qkv, const float* __restrict__ sink,
    u16* __restrict__ y, const int* __restrict__ slide_p,
    const int* __restrict__ win_p){
  __shared__ u16 Ks[64][72];
  __shared__ u16 VTs[64][72];
  __shared__ u16 Plds[4][32][72];

  int bid = blockIdx.x;
  int qt = bid & 7, h = (bid >> 3) & 63, b = bid >> 9;
  int t0 = qt << 7;
  int g = h >> 3;
  int kcol = 4096 + g * 64, vcol = 4608 + g * 64;
  int tid = threadIdx.x, w = tid >> 6, l = tid & 63;
  int lr = l & 15, lh = l >> 4;
  int win = (*slide_p) ? (*win_p) : (1 << 30);
  int tq0 = t0 + w * 32;

  bf16x8 qf[2][2];
#pragma unroll
  for (int m = 0; m < 2; m++)
#pragma unroll
    for (int kk = 0; kk < 2; kk++){
      int q = tq0 + m * 16 + lr;
      qf[m][kk] = *(const bf16x8*)&qkv[(size_t)(b * 1024 + q) * 5120 + h * 64 + kk * 32 + lh * 8];
    }

  float run_max[2] = {-1e30f, -1e30f};
  float run_sum[2] = {0.f, 0.f};
  f32x4 acc_o[4][2];
#pragma unroll
  for (int dt = 0; dt < 4; dt++)
#pragma unroll
    for (int m = 0; m < 2; m++){ acc_o[dt][m][0]=0.f; acc_o[dt][m][1]=0.f; acc_o[dt][m][2]=0.f; acc_o[dt][m][3]=0.f; }

  for (int c = 0; c < 4; c++){
    int key0 = t0 - 128 + c * 64;
#pragma unroll
    for (int it = 0; it < 2; ++it){
      int idx = it * 256 + tid;
      int key = idx >> 3, dd = (idx & 7) << 3;
      int gk = key0 + key;
      uint4 kq = make_uint4(0, 0, 0, 0);
      uint4 vq = make_uint4(0, 0, 0, 0);
      if (gk >= 0){
        size_t rb = (size_t)(b * 1024 + gk) * 5120;
        kq = *(const uint4*)&qkv[rb + kcol + dd];
        vq = *(const uint4*)&qkv[rb + vcol + dd];
      }
      *(uint4*)&Ks[key][dd] = kq;
      const u16* tv = (const u16*)&vq;
#pragma unroll
      for (int j = 0; j < 8; j++) VTs[dd + j][key] = tv[j];
    }
    __syncthreads();

    bool rel = (key0 + 63 >= tq0 - (win - 1)) && (key0 <= tq0 + 31);
    if (rel){
      f32x4 sacc[2][4];
#pragma unroll
      for (int m = 0; m < 2; m++)
#pragma unroll
        for (int n = 0; n < 4; n++){ sacc[m][n][0]=0.f; sacc[m][n][1]=0.f; sacc[m][n][2]=0.f; sacc[m][n][3]=0.f; }
#pragma unroll
      for (int kk = 0; kk < 2; kk++){
#pragma unroll
        for (int n = 0; n < 4; n++){
          bf16x8 kf = *(const bf16x8*)&Ks[n * 16 + lr][kk * 32 + lh * 8];
          sacc[0][n] = MFMA16(kf, qf[0][kk], sacc[0][n]);
          sacc[1][n] = MFMA16(kf, qf[1][kk], sacc[1][n]);
        }
      }
#pragma unroll
      for (int m = 0; m < 2; m++){
        int qrow = tq0 + m * 16 + lr;
        float cmax = -INFINITY;
#pragma unroll
        for (int n = 0; n < 4; n++)
#pragma unroll
          for (int r = 0; r < 4; r++){
            int key = key0 + n * 16 + lh * 4 + r;
            float s = scrub(sacc[m][n][r] * 0.125f, 1e30f);
            bool valid = (key >= 0) && (key <= qrow) && (qrow - key < win);
            s = valid ? s : -INFINITY;
            sacc[m][n][r] = s;
            cmax = fmaxf(cmax, s);
          }
        cmax = fmaxf(cmax, __shfl_xor(cmax, 16));
        cmax = fmaxf(cmax, __shfl_xor(cmax, 32));
        float mnew = fmaxf(run_max[m], cmax);
        float corr = __expf(run_max[m] - mnew);
        run_max[m] = mnew;
        float rsum = 0.f;
#pragma unroll
        for (int n = 0; n < 4; n++)
#pragma unroll
          for (int r = 0; r < 4; r++){
            float p = __expf(sacc[m][n][r] - mnew);
            sacc[m][n][r] = p;
            rsum += p;
          }
        rsum += __shfl_xor(rsum, 16);
        rsum += __shfl_xor(rsum, 32);
        run_sum[m] = run_sum[m] * corr + rsum;
#pragma unroll
        for (int dt = 0; dt < 4; dt++) acc_o[dt][m] *= corr;
#pragma unroll
        for (int n = 0; n < 4; n++)
#pragma unroll
          for (int r = 0; r < 4; r++)
            Plds[w][m * 16 + lr][n * 16 + lh * 4 + r] = f2b(sacc[m][n][r]);
      }
#pragma unroll
      for (int ks = 0; ks < 2; ks++){
        bf16x8 pb[2];
#pragma unroll
        for (int m = 0; m < 2; m++)
          pb[m] = *(const bf16x8*)&Plds[w][m * 16 + lr][ks * 32 + lh * 8];
#pragma unroll
        for (int dt = 0; dt < 4; dt++){
          bf16x8 vf = *(const bf16x8*)&VTs[dt * 16 + lr][ks * 32 + lh * 8];
          acc_o[dt][0] = MFMA16(vf, pb[0], acc_o[dt][0]);
          acc_o[dt][1] = MFMA16(vf, pb[1], acc_o[dt][1]);
        }
      }
    }
    __syncthreads();
  }

  float sk = sink[h];
  float osc[2];
#pragma unroll
  for (int m = 0; m < 2; m++){
    float Mf = fmaxf(run_max[m], sk);
    float t = __expf(run_max[m] - Mf);
    float denom = run_sum[m] * t + __expf(sk - Mf);
    osc[m] = t / denom;
  }
#pragma unroll
  for (int dt = 0; dt < 4; dt++)
#pragma unroll
    for (int m = 0; m < 2; m++)
#pragma unroll
      for (int r = 0; r < 4; r++){
        int d = dt * 16 + lh * 4 + r;
        int q = tq0 + m * 16 + lr;
        y[(size_t)(b * 1024 + q) * 4096 + h * 64 + d] = f2b(scrub(acc_o[dt][m][r] * osc[m], 1e9f));
      }
}

// ---------------- host ----------------
extern "C" void kernel_launch(void* const* d_in, const int* in_sizes, int n_in,
                              void* d_out, int out_size, void* d_ws, size_t ws_size,
                              hipStream_t stream){
  const float* x    = (const float*)d_in[0];
  const int*   pos  = (const int*)d_in[1];
  const float* Wq   = (const float*)d_in[3];
  const float* bq   = (const float*)d_in[4];
  const float* Wk   = (const float*)d_in[5];
  const float* bk   = (const float*)d_in[6];
  const float* Wv   = (const float*)d_in[7];
  const float* bv   = (const float*)d_in[8];
  const float* Wo   = (const float*)d_in[9];
  const float* bo   = (const float*)d_in[10];
  const float* sink = (const float*)d_in[11];
  const int* slide  = (const int*)d_in[12];
  const int* winp   = (const int*)d_in[13];
  float* out = (float*)d_out;

  // Workspace (62.26 MB peak):
  //   [0, 11.80M)           xb [2048][2880] bf16
  //   [11.80M, 17.69M)      wkvT [1024][2880] bf16 (dead after gemm1)
  //   [0, 16.78M)           ybuf [2048][4096] bf16 (attn out; xb+wkvT dead)
  //   [17.69M, 38.67M)      qkv [2048][5120] bf16
  //   [38.67M, 62.26M)      wqT -> woT [.][.] bf16 (sequential reuse)
  char* ws = (char*)d_ws;
  u16* xb   = (u16*)(ws + 0);
  u16* ybuf = (u16*)(ws + 0);
  u16* wkvT = (u16*)(ws + 11796480);
  u16* qkv  = (u16*)(ws + 17694720);
  u16* wqT  = (u16*)(ws + 38666240);
  u16* woT  = (u16*)(ws + 38666240);

  // prep1: x->bf16 + WqT ; prep2: WkT+WvT
  k_prep1<<<5760 + 11520, 256, 0, stream>>>(xb, x, wqT, Wq);
  k_prep2<<<1440 + 1440, 256, 0, stream>>>(wkvT, Wk, Wv);
  // Fused QKV projection + RoPE: M=2048, N=5120, K=2880 -> 8x40 = 320 WGs
  k_g4w<0, 1><<<320, 256, 0, stream>>>(xb, wqT, wkvT, bq, bk, bv, qkv, pos, 2048, 5120, 2880, 5120);
  // prep3: WoT (W region dead after gemm1)
  k_prep3<<<11520, 256, 0, stream>>>(woT, Wo);
  // attention
  k_attn<<<1024, 256, 0, stream>>>(qkv, sink, ybuf, slide, winp);
  // output projection: M=2048, N=2880, K=4096 -> 8x23 = 184 WGs (fp32 out)
  k_g4w<1, 0><<<184, 256, 0, stream>>>(ybuf, woT, woT, bo, bo, bo, out, pos, 2048, 2880, 4096, 2880);
}

// Round 10
// 212.692 us; speedup vs baseline: 1.2125x; 1.2125x over previous
//
#include <hip/hip_runtime.h>

typedef unsigned short u16;
typedef __attribute__((ext_vector_type(8))) short bf16x8;
typedef __attribute__((ext_vector_type(4))) float f32x4;

#define MFMA16(a,b,c) __builtin_amdgcn_mfma_f32_16x16x32_bf16((a),(b),(c),0,0,0)

__device__ __forceinline__ float b2f(u16 u){
  unsigned v = ((unsigned)u) << 16; float f;
  __builtin_memcpy(&f, &v, 4); return f;
}
__device__ __forceinline__ u16 f2b(float f){
  unsigned v; __builtin_memcpy(&v, &f, 4);
  v += 0x7FFFu + ((v >> 16) & 1u);
  return (u16)(v >> 16);
}
__device__ __forceinline__ float scrub(float v, float lim){
  return fminf(fmaxf(v, -lim), lim);   // NaN-filtering clamp
}
__device__ __forceinline__ void gload16(const void* g, void* l){
  __builtin_amdgcn_global_load_lds(
      (const __attribute__((address_space(1))) unsigned int*)g,
      (__attribute__((address_space(3))) unsigned int*)l, 16, 0, 0);
}

// ---- convert+transpose tile helper: dst[c][r] = bf16(src[r][c]) ----
__device__ __forceinline__ void cvtT_tile(float (*tile)[33],
    u16* __restrict__ dst, const float* __restrict__ src,
    int rows, int cols, int bx, int by, int tid){
  int n0 = bx * 32, r0 = by * 32;
  int tx = tid & 31, ty = tid >> 5;
#pragma unroll
  for (int i = 0; i < 4; i++)
    tile[ty + i * 8][tx] = src[(size_t)(r0 + ty + i * 8) * cols + n0 + tx];
  __syncthreads();
#pragma unroll
  for (int i = 0; i < 4; i++)
    dst[(size_t)(n0 + ty + i * 8) * rows + r0 + tx] = f2b(tile[tx][ty + i * 8]);
}

// ---- prep1: x -> bf16 (5760 blocks) + WqT (11520 blocks) ----
__global__ __launch_bounds__(256) void k_prep1(
    u16* __restrict__ xb, const float* __restrict__ x,
    u16* __restrict__ wqT, const float* __restrict__ Wq){
  __shared__ float tile[32][33];
  int b = blockIdx.x, tid = threadIdx.x;
  if (b < 5760){
    int i = b * 256 + tid;
    float4 v = ((const float4*)x)[i];
    u16 o[4] = { f2b(v.x), f2b(v.y), f2b(v.z), f2b(v.w) };
    *(uint2*)&xb[(size_t)i * 4] = *(const uint2*)o;
    return;
  }
  b -= 5760;
  cvtT_tile(tile, wqT, Wq, 2880, 4096, b % 128, b / 128, tid);
}

// ---- prep2: WkT + WvT (1440 each) ----
__global__ __launch_bounds__(256) void k_prep2(
    u16* __restrict__ wkvT, const float* __restrict__ Wk,
    const float* __restrict__ Wv){
  __shared__ float tile[32][33];
  int b = blockIdx.x, tid = threadIdx.x;
  if (b < 1440){ cvtT_tile(tile, wkvT, Wk, 2880, 512, b % 16, b / 16, tid); return; }
  b -= 1440;
  cvtT_tile(tile, wkvT + (size_t)512 * 2880, Wv, 2880, 512, b % 16, b / 16, tid);
}

// ---- prep3: WoT (11520 blocks) ----
__global__ __launch_bounds__(256) void k_prep3(
    u16* __restrict__ woT, const float* __restrict__ Wo){
  __shared__ float tile[32][33];
  int b = blockIdx.x, tid = threadIdx.x;
  cvtT_tile(tile, woT, Wo, 4096, 2880, b % 90, b / 90, tid);
}

// ======== ring-3 GEMM: BM=128, BN=128, BK=32, 256 thr (4 waves 2x2) ========
// Small-LDS (48KB) 3-buffer ring -> 3 blocks/CU co-resident (cross-block
// overlap hides barrier/vmcnt stalls, m97 mechanism). Counted vmcnt(4),
// one barrier per K-tile, 16B-granule XOR swizzle (2-way = free), setprio.
// B rows >= 4096 come from BT2 (fused KV projection).
template<int F32OUT, int ROPE>
__global__ __launch_bounds__(256, 3) void k_r3(
    const u16* __restrict__ A, const u16* __restrict__ BT, const u16* __restrict__ BT2,
    const float* __restrict__ b0, const float* __restrict__ b1, const float* __restrict__ b2,
    void* __restrict__ C, const int* __restrict__ pos, int M, int N, int K, int ldc){
  __shared__ u16 lds[3][8192];   // per buf: A[128][32] @0, B[128][32] @4096

  const int tid = threadIdx.x;
  const int w = tid >> 6, l = tid & 63;
  const int wm = w >> 1, wn = w & 1;      // 2x2 waves, per-wave 64x64
  const int lr = l & 15, lh = l >> 4;
  const int bid = blockIdx.x;
  const int mt = bid & 15, nt = bid >> 4; // M = 2048 -> 16 mt
  const int m0 = mt << 7, n0 = nt << 7;

  const int sr = tid >> 2;                // staging row 0..63 (+64 second half)
  const int sg = tid & 3;                 // staging granule 0..3
  const int rg = (lr >> 1) & 3;           // read-side granule XOR

  f32x4 acc[4][4];
#pragma unroll
  for (int mm = 0; mm < 4; mm++)
#pragma unroll
    for (int nn = 0; nn < 4; nn++){ acc[mm][nn][0]=0.f; acc[mm][nn][1]=0.f; acc[mm][nn][2]=0.f; acc[mm][nn][3]=0.f; }

#define STAGE_A(b, kt) { \
  int r1_ = sr, r2_ = sr + 64; \
  gload16(&A[(size_t)(m0 + r1_) * K + (kt) + ((sg ^ ((r1_>>1)&3)) << 3)], \
          (void*)&lds[b][r1_ * 32 + (sg << 3)]); \
  gload16(&A[(size_t)(m0 + r2_) * K + (kt) + ((sg ^ ((r2_>>1)&3)) << 3)], \
          (void*)&lds[b][r2_ * 32 + (sg << 3)]); }

#define STAGE_B(b, kt) { \
  int r1_ = n0 + sr, r2_ = n0 + sr + 64; \
  if (r1_ > N - 1) r1_ = N - 1; \
  if (r2_ > N - 1) r2_ = N - 1; \
  const u16* p1_ = BT; int q1_ = r1_; \
  if (q1_ >= 4096){ p1_ = BT2; q1_ -= 4096; } \
  const u16* p2_ = BT; int q2_ = r2_; \
  if (q2_ >= 4096){ p2_ = BT2; q2_ -= 4096; } \
  gload16(&p1_[(size_t)q1_ * K + (kt) + ((sg ^ ((sr>>1)&3)) << 3)], \
          (void*)&lds[b][4096 + sr * 32 + (sg << 3)]); \
  gload16(&p2_[(size_t)q2_ * K + (kt) + ((sg ^ ((sr>>1)&3)) << 3)], \
          (void*)&lds[b][4096 + (sr + 64) * 32 + (sg << 3)]); }

#define RD_A(dst, b, mm) dst = *(const bf16x8*)&lds[b][(wm*64 + (mm)*16 + lr) * 32 + ((lh ^ rg) << 3)]
#define RD_B(dst, b, nn) dst = *(const bf16x8*)&lds[b][4096 + (wn*64 + (nn)*16 + lr) * 32 + ((lh ^ rg) << 3)]

  const int NT = K >> 5;
  // prologue: stage tiles 0,1 into bufs 0,1 (4 loads each)
  STAGE_A(0, 0); STAGE_B(0, 0);
  STAGE_A(1, 32); STAGE_B(1, 32);
  asm volatile("s_waitcnt vmcnt(4)" ::: "memory");   // tile 0 complete
  __builtin_amdgcn_s_barrier();

  int cb = 0;
  for (int t = 0; t < NT; ++t){
    int sb = cb + 2; if (sb >= 3) sb -= 3;
    const bool ds = (t + 2) < NT;
    if (ds){ int kt2 = (t + 2) << 5; STAGE_A(sb, kt2); STAGE_B(sb, kt2); }

    bf16x8 af[4], bfr[4];
    RD_A(af[0], cb, 0); RD_A(af[1], cb, 1); RD_A(af[2], cb, 2); RD_A(af[3], cb, 3);
    RD_B(bfr[0], cb, 0); RD_B(bfr[1], cb, 1); RD_B(bfr[2], cb, 2); RD_B(bfr[3], cb, 3);
    __builtin_amdgcn_s_setprio(1);
#pragma unroll
    for (int mm = 0; mm < 4; mm++)
#pragma unroll
      for (int nn = 0; nn < 4; nn++)
        acc[mm][nn] = MFMA16(af[mm], bfr[nn], acc[mm][nn]);
    __builtin_amdgcn_s_setprio(0);

    if (ds) asm volatile("s_waitcnt vmcnt(4)" ::: "memory");
    else    asm volatile("s_waitcnt vmcnt(0)" ::: "memory");
    __builtin_amdgcn_s_barrier();
    cb += 1; if (cb >= 3) cb -= 3;
  }

  // ---- epilogue ----
#pragma unroll
  for (int mm = 0; mm < 4; mm++){
    int grow = m0 + wm * 64 + mm * 16 + (lh << 2);
#pragma unroll
    for (int nn = 0; nn < 4; nn++){
      int gcol = n0 + wn * 64 + nn * 16 + lr;
      if (gcol < N){
        float bs = (gcol < 4096) ? b0[gcol] : ((gcol < 4608) ? b1[gcol - 4096] : b2[gcol - 4608]);
        if (ROPE && gcol < 4608){
          int ii = (gcol & 63) >> 1;
          float inv = exp2f(-0.53733146f * (float)ii);
          float sgn = (lr & 1) ? 1.f : -1.f;
#pragma unroll
          for (int r = 0; r < 4; r++){
            float v = acc[mm][nn][r] + bs;
            float ang = (float)pos[grow + r] * 0.03125f * inv;
            float s, c; __sincosf(ang, &s, &c);
            float p = __shfl_xor(v, 1);
            v = v * c + p * sgn * s;
            ((u16*)C)[(size_t)(grow + r) * ldc + gcol] = f2b(scrub(v, 1e9f));
          }
        } else {
#pragma unroll
          for (int r = 0; r < 4; r++){
            float v = scrub(acc[mm][nn][r] + bs, 1e9f);
            size_t off = (size_t)(grow + r) * ldc + gcol;
            if (F32OUT) ((float*)C)[off] = v;
            else        ((u16*)C)[off]   = f2b(v);
          }
        }
      }
    }
  }
#undef STAGE_A
#undef STAGE_B
#undef RD_A
#undef RD_B
}

// ======== round-8 GEMM (kept for gemm2 A/B): BM=256, BN=128, BK=64, 512 thr ========
template<int F32OUT, int ROPE>
__global__ __launch_bounds__(512, 1) void k_gemm8p(
    const u16* __restrict__ A, const u16* __restrict__ BT,
    const float* __restrict__ bias, void* __restrict__ C,
    const int* __restrict__ pos, int M, int N, int K, int ldc){
  __shared__ u16 lds[3][24576];   // per buf: A[256][64] @0, B[128][64] @16384

  const int tid = threadIdx.x;
  const int w = tid >> 6, l = tid & 63;
  const int wm = w >> 1, wn = w & 1;
  const int lr = l & 15, lh = l >> 4;
  const int bid = blockIdx.x;
  const int mt = bid & 7, nt = bid >> 3;
  const int m0 = mt << 8, n0 = nt << 7;

  const int srow = tid >> 3;
  const int skc  = (tid & 7) << 3;
  const int ssw  = (srow & 7) << 3;
  const int rsw  = (lr & 7) << 3;

  f32x4 acc[4][4];
#pragma unroll
  for (int mm = 0; mm < 4; mm++)
#pragma unroll
    for (int nn = 0; nn < 4; nn++){ acc[mm][nn][0]=0.f; acc[mm][nn][1]=0.f; acc[mm][nn][2]=0.f; acc[mm][nn][3]=0.f; }

#define STAGE_A(b, kt, c) \
  gload16(&A[(size_t)(m0 + (c)*64 + srow) * K + (kt) + (skc ^ ssw)], \
          (void*)&lds[b][((c)*64 + srow) * 64 + skc])
#define STAGE_B(b, kt, c) { \
  int _r = n0 + (c)*64 + srow; if (_r > N - 1) _r = N - 1; \
  gload16(&BT[(size_t)_r * K + (kt) + (skc ^ ssw)], \
          (void*)&lds[b][16384 + ((c)*64 + srow) * 64 + skc]); }

#define RD_A(dst, As, mm, kk) dst = *(const bf16x8*)&(As)[((wm<<6) + ((mm)<<4) + lr) * 64 + ((((kk)<<5) + (lh<<3)) ^ rsw)]
#define RD_B(dst, Bs, nn, kk) dst = *(const bf16x8*)&(Bs)[((wn<<6) + ((nn)<<4) + lr) * 64 + ((((kk)<<5) + (lh<<3)) ^ rsw)]

  const int NT = K >> 6;
#pragma unroll
  for (int tt = 0; tt < 2; ++tt){
    int kt = tt << 6;
    STAGE_A(tt, kt, 0); STAGE_A(tt, kt, 1); STAGE_A(tt, kt, 2); STAGE_A(tt, kt, 3);
    STAGE_B(tt, kt, 0); STAGE_B(tt, kt, 1);
  }
  asm volatile("s_waitcnt vmcnt(6)" ::: "memory");
  __builtin_amdgcn_s_barrier();

  int cb = 0;
  for (int t = 0; t < NT; ++t){
    const u16* As = &lds[cb][0];
    const u16* Bs = &lds[cb][16384];
    int sb = cb + 2; if (sb >= 3) sb -= 3;
    const int kt2 = (t + 2) << 6;
    const bool do_stage = (t + 2) < NT;

    bf16x8 a00,a01,a10,a11,a20,a21,a30,a31, b00,b01,b10,b11;
    RD_A(a00, As, 0, 0); RD_A(a01, As, 0, 1);
    RD_A(a10, As, 1, 0); RD_A(a11, As, 1, 1);
    RD_A(a20, As, 2, 0); RD_A(a21, As, 2, 1);
    RD_A(a30, As, 3, 0); RD_A(a31, As, 3, 1);
    RD_B(b00, Bs, 0, 0); RD_B(b01, Bs, 0, 1);
    RD_B(b10, Bs, 1, 0); RD_B(b11, Bs, 1, 1);
    if (do_stage){ STAGE_A(sb, kt2, 0); STAGE_A(sb, kt2, 1); }
    __builtin_amdgcn_s_setprio(1);
    acc[0][0]=MFMA16(a00,b00,acc[0][0]);
    acc[1][0]=MFMA16(a10,b00,acc[1][0]);
    acc[2][0]=MFMA16(a20,b00,acc[2][0]);
    acc[3][0]=MFMA16(a30,b00,acc[3][0]);
    acc[0][1]=MFMA16(a00,b10,acc[0][1]);
    acc[1][1]=MFMA16(a10,b10,acc[1][1]);
    acc[2][1]=MFMA16(a20,b10,acc[2][1]);
    acc[3][1]=MFMA16(a30,b10,acc[3][1]);
    acc[0][0]=MFMA16(a01,b01,acc[0][0]);
    acc[1][0]=MFMA16(a11,b01,acc[1][0]);
    acc[2][0]=MFMA16(a21,b01,acc[2][0]);
    acc[3][0]=MFMA16(a31,b01,acc[3][0]);
    acc[0][1]=MFMA16(a01,b11,acc[0][1]);
    acc[1][1]=MFMA16(a11,b11,acc[1][1]);
    acc[2][1]=MFMA16(a21,b11,acc[2][1]);
    acc[3][1]=MFMA16(a31,b11,acc[3][1]);
    __builtin_amdgcn_s_setprio(0);

    RD_B(b00, Bs, 2, 0); RD_B(b01, Bs, 2, 1);
    RD_B(b10, Bs, 3, 0); RD_B(b11, Bs, 3, 1);
    if (do_stage){ STAGE_A(sb, kt2, 2); STAGE_A(sb, kt2, 3); }
    __builtin_amdgcn_s_setprio(1);
    acc[0][2]=MFMA16(a00,b00,acc[0][2]);
    acc[1][2]=MFMA16(a10,b00,acc[1][2]);
    acc[2][2]=MFMA16(a20,b00,acc[2][2]);
    acc[3][2]=MFMA16(a30,b00,acc[3][2]);
    acc[0][3]=MFMA16(a00,b10,acc[0][3]);
    acc[1][3]=MFMA16(a10,b10,acc[1][3]);
    acc[2][3]=MFMA16(a20,b10,acc[2][3]);
    acc[3][3]=MFMA16(a30,b10,acc[3][3]);
    acc[0][2]=MFMA16(a01,b01,acc[0][2]);
    acc[1][2]=MFMA16(a11,b01,acc[1][2]);
    acc[2][2]=MFMA16(a21,b01,acc[2][2]);
    acc[3][2]=MFMA16(a31,b01,acc[3][2]);
    acc[0][3]=MFMA16(a01,b11,acc[0][3]);
    acc[1][3]=MFMA16(a11,b11,acc[1][3]);
    acc[2][3]=MFMA16(a21,b11,acc[2][3]);
    acc[3][3]=MFMA16(a31,b11,acc[3][3]);
    __builtin_amdgcn_s_setprio(0);

    if (do_stage){ STAGE_B(sb, kt2, 0); STAGE_B(sb, kt2, 1); }

    if (do_stage) asm volatile("s_waitcnt vmcnt(6)" ::: "memory");
    else          asm volatile("s_waitcnt vmcnt(0)" ::: "memory");
    __builtin_amdgcn_s_barrier();

    cb += 1; if (cb >= 3) cb -= 3;
  }

#pragma unroll
  for (int mm = 0; mm < 4; mm++){
    int grow = m0 + (wm << 6) + (mm << 4) + (lh << 2);
#pragma unroll
    for (int nn = 0; nn < 4; nn++){
      int gcol = n0 + (wn << 6) + (nn << 4) + lr;
      if (gcol < N){
        float bs = bias[gcol];
#pragma unroll
        for (int r = 0; r < 4; r++){
          float v = scrub(acc[mm][nn][r] + bs, 1e9f);
          size_t off = (size_t)(grow + r) * ldc + gcol;
          if (F32OUT) ((float*)C)[off] = v;
          else        ((u16*)C)[off]   = f2b(v);
        }
      }
    }
  }
#undef STAGE_A
#undef STAGE_B
#undef RD_A
#undef RD_B
}

// ---------------- attention (unchanged, verified) ----------------
__global__ __launch_bounds__(256) void k_attn(
    const u16* __restrict__ qkv, const float* __restrict__ sink,
    u16* __restrict__ y, const int* __restrict__ slide_p,
    const int* __restrict__ win_p){
  __shared__ u16 Ks[64][72];
  __shared__ u16 VTs[64][72];
  __shared__ u16 Plds[4][32][72];

  int bid = blockIdx.x;
  int qt = bid & 7, h = (bid >> 3) & 63, b = bid >> 9;
  int t0 = qt << 7;
  int g = h >> 3;
  int kcol = 4096 + g * 64, vcol = 4608 + g * 64;
  int tid = threadIdx.x, w = tid >> 6, l = tid & 63;
  int lr = l & 15, lh = l >> 4;
  int win = (*slide_p) ? (*win_p) : (1 << 30);
  int tq0 = t0 + w * 32;

  bf16x8 qf[2][2];
#pragma unroll
  for (int m = 0; m < 2; m++)
#pragma unroll
    for (int kk = 0; kk < 2; kk++){
      int q = tq0 + m * 16 + lr;
      qf[m][kk] = *(const bf16x8*)&qkv[(size_t)(b * 1024 + q) * 5120 + h * 64 + kk * 32 + lh * 8];
    }

  float run_max[2] = {-1e30f, -1e30f};
  float run_sum[2] = {0.f, 0.f};
  f32x4 acc_o[4][2];
#pragma unroll
  for (int dt = 0; dt < 4; dt++)
#pragma unroll
    for (int m = 0; m < 2; m++){ acc_o[dt][m][0]=0.f; acc_o[dt][m][1]=0.f; acc_o[dt][m][2]=0.f; acc_o[dt][m][3]=0.f; }

  for (int c = 0; c < 4; c++){
    int key0 = t0 - 128 + c * 64;
#pragma unroll
    for (int it = 0; it < 2; ++it){
      int idx = it * 256 + tid;
      int key = idx >> 3, dd = (idx & 7) << 3;
      int gk = key0 + key;
      uint4 kq = make_uint4(0, 0, 0, 0);
      uint4 vq = make_uint4(0, 0, 0, 0);
      if (gk >= 0){
        size_t rb = (size_t)(b * 1024 + gk) * 5120;
        kq = *(const uint4*)&qkv[rb + kcol + dd];
        vq = *(const uint4*)&qkv[rb + vcol + dd];
      }
      *(uint4*)&Ks[key][dd] = kq;
      const u16* tv = (const u16*)&vq;
#pragma unroll
      for (int j = 0; j < 8; j++) VTs[dd + j][key] = tv[j];
    }
    __syncthreads();

    bool rel = (key0 + 63 >= tq0 - (win - 1)) && (key0 <= tq0 + 31);
    if (rel){
      f32x4 sacc[2][4];
#pragma unroll
      for (int m = 0; m < 2; m++)
#pragma unroll
        for (int n = 0; n < 4; n++){ sacc[m][n][0]=0.f; sacc[m][n][1]=0.f; sacc[m][n][2]=0.f; sacc[m][n][3]=0.f; }
#pragma unroll
      for (int kk = 0; kk < 2; kk++){
#pragma unroll
        for (int n = 0; n < 4; n++){
          bf16x8 kf = *(const bf16x8*)&Ks[n * 16 + lr][kk * 32 + lh * 8];
          sacc[0][n] = MFMA16(kf, qf[0][kk], sacc[0][n]);
          sacc[1][n] = MFMA16(kf, qf[1][kk], sacc[1][n]);
        }
      }
#pragma unroll
      for (int m = 0; m < 2; m++){
        int qrow = tq0 + m * 16 + lr;
        float cmax = -INFINITY;
#pragma unroll
        for (int n = 0; n < 4; n++)
#pragma unroll
          for (int r = 0; r < 4; r++){
            int key = key0 + n * 16 + lh * 4 + r;
            float s = scrub(sacc[m][n][r] * 0.125f, 1e30f);
            bool valid = (key >= 0) && (key <= qrow) && (qrow - key < win);
            s = valid ? s : -INFINITY;
            sacc[m][n][r] = s;
            cmax = fmaxf(cmax, s);
          }
        cmax = fmaxf(cmax, __shfl_xor(cmax, 16));
        cmax = fmaxf(cmax, __shfl_xor(cmax, 32));
        float mnew = fmaxf(run_max[m], cmax);
        float corr = __expf(run_max[m] - mnew);
        run_max[m] = mnew;
        float rsum = 0.f;
#pragma unroll
        for (int n = 0; n < 4; n++)
#pragma unroll
          for (int r = 0; r < 4; r++){
            float p = __expf(sacc[m][n][r] - mnew);
            sacc[m][n][r] = p;
            rsum += p;
          }
        rsum += __shfl_xor(rsum, 16);
        rsum += __shfl_xor(rsum, 32);
        run_sum[m] = run_sum[m] * corr + rsum;
#pragma unroll
        for (int dt = 0; dt < 4; dt++) acc_o[dt][m] *= corr;
#pragma unroll
        for (int n = 0; n < 4; n++)
#pragma unroll
          for (int r = 0; r < 4; r++)
            Plds[w][m * 16 + lr][n * 16 + lh * 4 + r] = f2b(sacc[m][n][r]);
      }
#pragma unroll
      for (int ks = 0; ks < 2; ks++){
        bf16x8 pb[2];
#pragma unroll
        for (int m = 0; m < 2; m++)
          pb[m] = *(const bf16x8*)&Plds[w][m * 16 + lr][ks * 32 + lh * 8];
#pragma unroll
        for (int dt = 0; dt < 4; dt++){
          bf16x8 vf = *(const bf16x8*)&VTs[dt * 16 + lr][ks * 32 + lh * 8];
          acc_o[dt][0] = MFMA16(vf, pb[0], acc_o[dt][0]);
          acc_o[dt][1] = MFMA16(vf, pb[1], acc_o[dt][1]);
        }
      }
    }
    __syncthreads();
  }

  float sk = sink[h];
  float osc[2];
#pragma unroll
  for (int m = 0; m < 2; m++){
    float Mf = fmaxf(run_max[m], sk);
    float t = __expf(run_max[m] - Mf);
    float denom = run_sum[m] * t + __expf(sk - Mf);
    osc[m] = t / denom;
  }
#pragma unroll
  for (int dt = 0; dt < 4; dt++)
#pragma unroll
    for (int m = 0; m < 2; m++)
#pragma unroll
      for (int r = 0; r < 4; r++){
        int d = dt * 16 + lh * 4 + r;
        int q = tq0 + m * 16 + lr;
        y[(size_t)(b * 1024 + q) * 4096 + h * 64 + d] = f2b(scrub(acc_o[dt][m][r] * osc[m], 1e9f));
      }
}

// ---------------- host ----------------
extern "C" void kernel_launch(void* const* d_in, const int* in_sizes, int n_in,
                              void* d_out, int out_size, void* d_ws, size_t ws_size,
                              hipStream_t stream){
  const float* x    = (const float*)d_in[0];
  const int*   pos  = (const int*)d_in[1];
  const float* Wq   = (const float*)d_in[3];
  const float* bq   = (const float*)d_in[4];
  const float* Wk   = (const float*)d_in[5];
  const float* bk   = (const float*)d_in[6];
  const float* Wv   = (const float*)d_in[7];
  const float* bv   = (const float*)d_in[8];
  const float* Wo   = (const float*)d_in[9];
  const float* bo   = (const float*)d_in[10];
  const float* sink = (const float*)d_in[11];
  const int* slide  = (const int*)d_in[12];
  const int* winp   = (const int*)d_in[13];
  float* out = (float*)d_out;

  // Workspace (62.26 MB peak, proven round 9):
  //   [0, 11.80M)       xb ; [0, 16.78M) ybuf (after xb/wkvT dead)
  //   [11.80M, 17.69M)  wkvT (dead after gemm1)
  //   [17.69M, 38.67M)  qkv
  //   [38.67M, 62.26M)  wqT -> woT (sequential reuse)
  char* ws = (char*)d_ws;
  u16* xb   = (u16*)(ws + 0);
  u16* ybuf = (u16*)(ws + 0);
  u16* wkvT = (u16*)(ws + 11796480);
  u16* qkv  = (u16*)(ws + 17694720);
  u16* wqT  = (u16*)(ws + 38666240);
  u16* woT  = (u16*)(ws + 38666240);

  // preps
  k_prep1<<<5760 + 11520, 256, 0, stream>>>(xb, x, wqT, Wq);
  k_prep2<<<1440 + 1440, 256, 0, stream>>>(wkvT, Wk, Wv);
  // Fused QKV projection + RoPE: M=2048, N=5120, K=2880 -> 16x40 = 640 WGs
  k_r3<0, 1><<<640, 256, 0, stream>>>(xb, wqT, wkvT, bq, bk, bv, qkv, pos, 2048, 5120, 2880, 5120);
  // prep3: WoT
  k_prep3<<<11520, 256, 0, stream>>>(woT, Wo);
  // attention
  k_attn<<<1024, 256, 0, stream>>>(qkv, sink, ybuf, slide, winp);
  // output projection (round-8 kernel, known-good): 8x23 = 184 WGs
  k_gemm8p<1, 0><<<184, 512, 0, stream>>>(ybuf, woT, bo, out, pos, 2048, 2880, 4096, 2880);
}

// Round 11
// 181.991 us; speedup vs baseline: 1.4171x; 1.1687x over previous
//
#include <hip/hip_runtime.h>

typedef unsigned short u16;
typedef __attribute__((ext_vector_type(8))) short bf16x8;
typedef __attribute__((ext_vector_type(4))) float f32x4;

#define MFMA16(a,b,c) __builtin_amdgcn_mfma_f32_16x16x32_bf16((a),(b),(c),0,0,0)

__device__ __forceinline__ float b2f(u16 u){
  unsigned v = ((unsigned)u) << 16; float f;
  __builtin_memcpy(&f, &v, 4); return f;
}
__device__ __forceinline__ u16 f2b(float f){
  unsigned v; __builtin_memcpy(&v, &f, 4);
  v += 0x7FFFu + ((v >> 16) & 1u);
  return (u16)(v >> 16);
}
__device__ __forceinline__ float scrub(float v, float lim){
  return fminf(fmaxf(v, -lim), lim);   // NaN-filtering clamp
}
__device__ __forceinline__ void gload16(const void* g, void* l){
  __builtin_amdgcn_global_load_lds(
      (const __attribute__((address_space(1))) unsigned int*)g,
      (__attribute__((address_space(3))) unsigned int*)l, 16, 0, 0);
}

// ---- convert+transpose tile helper: dst[c][r] = bf16(src[r][c]) ----
__device__ __forceinline__ void cvtT_tile(float (*tile)[33],
    u16* __restrict__ dst, const float* __restrict__ src,
    int rows, int cols, int bx, int by, int tid){
  int n0 = bx * 32, r0 = by * 32;
  int tx = tid & 31, ty = tid >> 5;
#pragma unroll
  for (int i = 0; i < 4; i++)
    tile[ty + i * 8][tx] = src[(size_t)(r0 + ty + i * 8) * cols + n0 + tx];
  __syncthreads();
#pragma unroll
  for (int i = 0; i < 4; i++)
    dst[(size_t)(n0 + ty + i * 8) * rows + r0 + tx] = f2b(tile[tx][ty + i * 8]);
}

// ---- prep1: x -> bf16 (5760 blocks) + WqT (11520 blocks) ----
__global__ __launch_bounds__(256) void k_prep1(
    u16* __restrict__ xb, const float* __restrict__ x,
    u16* __restrict__ wqT, const float* __restrict__ Wq){
  __shared__ float tile[32][33];
  int b = blockIdx.x, tid = threadIdx.x;
  if (b < 5760){
    int i = b * 256 + tid;
    float4 v = ((const float4*)x)[i];
    u16 o[4] = { f2b(v.x), f2b(v.y), f2b(v.z), f2b(v.w) };
    *(uint2*)&xb[(size_t)i * 4] = *(const uint2*)o;
    return;
  }
  b -= 5760;
  cvtT_tile(tile, wqT, Wq, 2880, 4096, b % 128, b / 128, tid);
}

// ---- prep2: WkT + WvT (1440 each) ----
__global__ __launch_bounds__(256) void k_prep2(
    u16* __restrict__ wkvT, const float* __restrict__ Wk,
    const float* __restrict__ Wv){
  __shared__ float tile[32][33];
  int b = blockIdx.x, tid = threadIdx.x;
  if (b < 1440){ cvtT_tile(tile, wkvT, Wk, 2880, 512, b % 16, b / 16, tid); return; }
  b -= 1440;
  cvtT_tile(tile, wkvT + (size_t)512 * 2880, Wv, 2880, 512, b % 16, b / 16, tid);
}

// ---- prep3: WoT (11520 blocks) ----
__global__ __launch_bounds__(256) void k_prep3(
    u16* __restrict__ woT, const float* __restrict__ Wo){
  __shared__ float tile[32][33];
  int b = blockIdx.x, tid = threadIdx.x;
  cvtT_tile(tile, woT, Wo, 4096, 2880, b % 90, b / 90, tid);
}

// ======== exact-fill GEMM: BM=256 x BN(160|96), BK=64, 512 thr (8 waves 4Mx2N) ====
// Proven 3-ring structure (R8): reads buf t, stages buf t+2, ONE barrier +
// counted vmcnt per K-tile, 16B k-XOR swizzle (0 conflicts), setprio.
// BN chosen so grid fills 256 CUs exactly (makespan quantization fix).
// B-tile = FULL x 64-row chunks (all 512 thr) + one 32-row chunk (tids<256).
// Per-wave loads/tile: A=4 uniform; B=FULL+1 (waves 0-3) or FULL (waves 4-7).
// vmcnt(4+FULL) == min per-wave count => every wave's t+1 loads drained
// before the barrier (per-wave FIFO vmcnt semantics), tile fully staged.
template<int BN, int F32OUT, int ROPE>
__global__ __launch_bounds__(512, 1) void k_gx(
    const u16* __restrict__ A, const u16* __restrict__ BT, const u16* __restrict__ BT2,
    const float* __restrict__ b0, const float* __restrict__ b1, const float* __restrict__ b2,
    void* __restrict__ C, const int* __restrict__ pos, int M, int N, int K, int ldc){
  constexpr int NF   = BN / 32;          // B frags per wave (per k-half)
  constexpr int FULL = (BN - 32) / 64;   // full 64-row B chunks
  constexpr int BUFE = 16384 + BN * 64;  // u16 elems per ring buf
  constexpr int VMW  = 4 + FULL;         // counted wait
  __shared__ u16 lds[3][BUFE];           // A[256][64] @0, B[BN][64] @16384

  const int tid = threadIdx.x;
  const int w = tid >> 6, l = tid & 63;
  const int wm = w >> 1, wn = w & 1;     // 4 x 2 waves; per-wave 64 x BN/2
  const int lr = l & 15, lh = l >> 4;
  const int bid = blockIdx.x;
  const int mt = bid & 7, nt = bid >> 3; // M=2048 -> 8 mt
  const int m0 = mt << 8, n0 = nt * BN;

  const int srow = tid >> 3;             // 0..63
  const int skc  = (tid & 7) << 3;       // 0,8,..,56 elems
  const int ssw  = (srow & 7) << 3;      // stage-source k swizzle
  const int rsw  = (lr & 7) << 3;        // read-side k swizzle
  const int rrow = tid >> 3;             // rem-chunk row (tids<256 -> 0..31)

  f32x4 acc[4][NF];
#pragma unroll
  for (int mm = 0; mm < 4; mm++)
#pragma unroll
    for (int nn = 0; nn < NF; nn++){ acc[mm][nn][0]=0.f; acc[mm][nn][1]=0.f; acc[mm][nn][2]=0.f; acc[mm][nn][3]=0.f; }

#define STAGE_A(b, kt, c) \
  gload16(&A[(size_t)(m0 + (c)*64 + srow) * K + (kt) + (skc ^ ssw)], \
          (void*)&lds[b][((c)*64 + srow) * 64 + skc])
#define STAGE_BF(b, kt, c) { \
  int _r = n0 + (c)*64 + srow; \
  const u16* _bt = BT; if (ROPE && _r >= 4096){ _bt = BT2; _r -= 4096; } \
  gload16(&_bt[(size_t)_r * K + (kt) + (skc ^ ssw)], \
          (void*)&lds[b][16384 + ((c)*64 + srow) * 64 + skc]); }
#define STAGE_BR(b, kt) if (tid < 256){ \
  int _r = n0 + FULL*64 + rrow; \
  const u16* _bt = BT; if (ROPE && _r >= 4096){ _bt = BT2; _r -= 4096; } \
  gload16(&_bt[(size_t)_r * K + (kt) + (skc ^ ((rrow & 7) << 3))], \
          (void*)&lds[b][16384 + (FULL*64 + rrow) * 64 + skc]); }

#define RD_A(dst, b, mm, kk) dst = *(const bf16x8*)&lds[b][((wm<<6) + ((mm)<<4) + lr) * 64 + ((((kk)<<5) + (lh<<3)) ^ rsw)]
#define RD_B(dst, b, nn, kk) dst = *(const bf16x8*)&lds[b][16384 + (wn*(BN/2) + (nn)*16 + lr) * 64 + ((((kk)<<5) + (lh<<3)) ^ rsw)]

  const int NT = K >> 6;
  // prologue: stage tiles 0,1 into bufs 0,1
#pragma unroll
  for (int tt = 0; tt < 2; ++tt){
    int kt = tt << 6;
#pragma unroll
    for (int c = 0; c < 4; ++c) STAGE_A(tt, kt, c);
#pragma unroll
    for (int c = 0; c < FULL; ++c) STAGE_BF(tt, kt, c);
    STAGE_BR(tt, kt);
  }
  asm volatile("s_waitcnt vmcnt(%0)" :: "i"(VMW) : "memory");   // tile 0 complete
  __builtin_amdgcn_s_barrier();

  int cb = 0;
  for (int t = 0; t < NT; ++t){
    int sb = cb + 2; if (sb >= 3) sb -= 3;
    const int kt2 = (t + 2) << 6;
    const bool ds = (t + 2) < NT;

    bf16x8 bf[NF][2];
#pragma unroll
    for (int nn = 0; nn < NF; nn++){ RD_B(bf[nn][0], cb, nn, 0); RD_B(bf[nn][1], cb, nn, 1); }

#pragma unroll
    for (int mm = 0; mm < 4; mm++){
      bf16x8 a0, a1;
      RD_A(a0, cb, mm, 0); RD_A(a1, cb, mm, 1);
      if (ds){
        STAGE_A(sb, kt2, mm);
        if (mm < FULL) STAGE_BF(sb, kt2, mm);
        if (mm == 2) STAGE_BR(sb, kt2);
      }
      __builtin_amdgcn_s_setprio(1);
#pragma unroll
      for (int nn = 0; nn < NF; nn++) acc[mm][nn] = MFMA16(a0, bf[nn][0], acc[mm][nn]);
#pragma unroll
      for (int nn = 0; nn < NF; nn++) acc[mm][nn] = MFMA16(a1, bf[nn][1], acc[mm][nn]);
      __builtin_amdgcn_s_setprio(0);
    }

    if (ds) asm volatile("s_waitcnt vmcnt(%0)" :: "i"(VMW) : "memory");
    else    asm volatile("s_waitcnt vmcnt(0)" ::: "memory");
    __builtin_amdgcn_s_barrier();
    cb += 1; if (cb >= 3) cb -= 3;
  }

  // ---- epilogue ----
#pragma unroll
  for (int mm = 0; mm < 4; mm++){
    int grow = m0 + (wm << 6) + (mm << 4) + (lh << 2);
#pragma unroll
    for (int nn = 0; nn < NF; nn++){
      int gcol = n0 + wn * (BN / 2) + nn * 16 + lr;
      float bs;
      if (ROPE) bs = (gcol < 4096) ? b0[gcol] : ((gcol < 4608) ? b1[gcol - 4096] : b2[gcol - 4608]);
      else      bs = b0[gcol];
      if (ROPE && gcol < 4608){
        int ii = (gcol & 63) >> 1;
        float inv = exp2f(-0.53733146f * (float)ii);
        float sgn = (lr & 1) ? 1.f : -1.f;
#pragma unroll
        for (int r = 0; r < 4; r++){
          float v = acc[mm][nn][r] + bs;
          float ang = (float)pos[grow + r] * 0.03125f * inv;
          float s, c; __sincosf(ang, &s, &c);
          float p = __shfl_xor(v, 1);
          v = v * c + p * sgn * s;
          ((u16*)C)[(size_t)(grow + r) * ldc + gcol] = f2b(scrub(v, 1e9f));
        }
      } else {
#pragma unroll
        for (int r = 0; r < 4; r++){
          float v = scrub(acc[mm][nn][r] + bs, 1e9f);
          size_t off = (size_t)(grow + r) * ldc + gcol;
          if (F32OUT) ((float*)C)[off] = v;
          else        ((u16*)C)[off]   = f2b(v);
        }
      }
    }
  }
#undef STAGE_A
#undef STAGE_BF
#undef STAGE_BR
#undef RD_A
#undef RD_B
}

// ---------------- attention (unchanged, verified) ----------------
__global__ __launch_bounds__(256) void k_attn(
    const u16* __restrict__ qkv, const float* __restrict__ sink,
    u16* __restrict__ y, const int* __restrict__ slide_p,
    const int* __restrict__ win_p){
  __shared__ u16 Ks[64][72];
  __shared__ u16 VTs[64][72];
  __shared__ u16 Plds[4][32][72];

  int bid = blockIdx.x;
  int qt = bid & 7, h = (bid >> 3) & 63, b = bid >> 9;
  int t0 = qt << 7;
  int g = h >> 3;
  int kcol = 4096 + g * 64, vcol = 4608 + g * 64;
  int tid = threadIdx.x, w = tid >> 6, l = tid & 63;
  int lr = l & 15, lh = l >> 4;
  int win = (*slide_p) ? (*win_p) : (1 << 30);
  int tq0 = t0 + w * 32;

  bf16x8 qf[2][2];
#pragma unroll
  for (int m = 0; m < 2; m++)
#pragma unroll
    for (int kk = 0; kk < 2; kk++){
      int q = tq0 + m * 16 + lr;
      qf[m][kk] = *(const bf16x8*)&qkv[(size_t)(b * 1024 + q) * 5120 + h * 64 + kk * 32 + lh * 8];
    }

  float run_max[2] = {-1e30f, -1e30f};
  float run_sum[2] = {0.f, 0.f};
  f32x4 acc_o[4][2];
#pragma unroll
  for (int dt = 0; dt < 4; dt++)
#pragma unroll
    for (int m = 0; m < 2; m++){ acc_o[dt][m][0]=0.f; acc_o[dt][m][1]=0.f; acc_o[dt][m][2]=0.f; acc_o[dt][m][3]=0.f; }

  for (int c = 0; c < 4; c++){
    int key0 = t0 - 128 + c * 64;
#pragma unroll
    for (int it = 0; it < 2; ++it){
      int idx = it * 256 + tid;
      int key = idx >> 3, dd = (idx & 7) << 3;
      int gk = key0 + key;
      uint4 kq = make_uint4(0, 0, 0, 0);
      uint4 vq = make_uint4(0, 0, 0, 0);
      if (gk >= 0){
        size_t rb = (size_t)(b * 1024 + gk) * 5120;
        kq = *(const uint4*)&qkv[rb + kcol + dd];
        vq = *(const uint4*)&qkv[rb + vcol + dd];
      }
      *(uint4*)&Ks[key][dd] = kq;
      const u16* tv = (const u16*)&vq;
#pragma unroll
      for (int j = 0; j < 8; j++) VTs[dd + j][key] = tv[j];
    }
    __syncthreads();

    bool rel = (key0 + 63 >= tq0 - (win - 1)) && (key0 <= tq0 + 31);
    if (rel){
      f32x4 sacc[2][4];
#pragma unroll
      for (int m = 0; m < 2; m++)
#pragma unroll
        for (int n = 0; n < 4; n++){ sacc[m][n][0]=0.f; sacc[m][n][1]=0.f; sacc[m][n][2]=0.f; sacc[m][n][3]=0.f; }
#pragma unroll
      for (int kk = 0; kk < 2; kk++){
#pragma unroll
        for (int n = 0; n < 4; n++){
          bf16x8 kf = *(const bf16x8*)&Ks[n * 16 + lr][kk * 32 + lh * 8];
          sacc[0][n] = MFMA16(kf, qf[0][kk], sacc[0][n]);
          sacc[1][n] = MFMA16(kf, qf[1][kk], sacc[1][n]);
        }
      }
#pragma unroll
      for (int m = 0; m < 2; m++){
        int qrow = tq0 + m * 16 + lr;
        float cmax = -INFINITY;
#pragma unroll
        for (int n = 0; n < 4; n++)
#pragma unroll
          for (int r = 0; r < 4; r++){
            int key = key0 + n * 16 + lh * 4 + r;
            float s = scrub(sacc[m][n][r] * 0.125f, 1e30f);
            bool valid = (key >= 0) && (key <= qrow) && (qrow - key < win);
            s = valid ? s : -INFINITY;
            sacc[m][n][r] = s;
            cmax = fmaxf(cmax, s);
          }
        cmax = fmaxf(cmax, __shfl_xor(cmax, 16));
        cmax = fmaxf(cmax, __shfl_xor(cmax, 32));
        float mnew = fmaxf(run_max[m], cmax);
        float corr = __expf(run_max[m] - mnew);
        run_max[m] = mnew;
        float rsum = 0.f;
#pragma unroll
        for (int n = 0; n < 4; n++)
#pragma unroll
          for (int r = 0; r < 4; r++){
            float p = __expf(sacc[m][n][r] - mnew);
            sacc[m][n][r] = p;
            rsum += p;
          }
        rsum += __shfl_xor(rsum, 16);
        rsum += __shfl_xor(rsum, 32);
        run_sum[m] = run_sum[m] * corr + rsum;
#pragma unroll
        for (int dt = 0; dt < 4; dt++) acc_o[dt][m] *= corr;
#pragma unroll
        for (int n = 0; n < 4; n++)
#pragma unroll
          for (int r = 0; r < 4; r++)
            Plds[w][m * 16 + lr][n * 16 + lh * 4 + r] = f2b(sacc[m][n][r]);
      }
#pragma unroll
      for (int ks = 0; ks < 2; ks++){
        bf16x8 pb[2];
#pragma unroll
        for (int m = 0; m < 2; m++)
          pb[m] = *(const bf16x8*)&Plds[w][m * 16 + lr][ks * 32 + lh * 8];
#pragma unroll
        for (int dt = 0; dt < 4; dt++){
          bf16x8 vf = *(const bf16x8*)&VTs[dt * 16 + lr][ks * 32 + lh * 8];
          acc_o[dt][0] = MFMA16(vf, pb[0], acc_o[dt][0]);
          acc_o[dt][1] = MFMA16(vf, pb[1], acc_o[dt][1]);
        }
      }
    }
    __syncthreads();
  }

  float sk = sink[h];
  float osc[2];
#pragma unroll
  for (int m = 0; m < 2; m++){
    float Mf = fmaxf(run_max[m], sk);
    float t = __expf(run_max[m] - Mf);
    float denom = run_sum[m] * t + __expf(sk - Mf);
    osc[m] = t / denom;
  }
#pragma unroll
  for (int dt = 0; dt < 4; dt++)
#pragma unroll
    for (int m = 0; m < 2; m++)
#pragma unroll
      for (int r = 0; r < 4; r++){
        int d = dt * 16 + lh * 4 + r;
        int q = tq0 + m * 16 + lr;
        y[(size_t)(b * 1024 + q) * 4096 + h * 64 + d] = f2b(scrub(acc_o[dt][m][r] * osc[m], 1e9f));
      }
}

// ---------------- host ----------------
extern "C" void kernel_launch(void* const* d_in, const int* in_sizes, int n_in,
                              void* d_out, int out_size, void* d_ws, size_t ws_size,
                              hipStream_t stream){
  const float* x    = (const float*)d_in[0];
  const int*   pos  = (const int*)d_in[1];
  const float* Wq   = (const float*)d_in[3];
  const float* bq   = (const float*)d_in[4];
  const float* Wk   = (const float*)d_in[5];
  const float* bk   = (const float*)d_in[6];
  const float* Wv   = (const float*)d_in[7];
  const float* bv   = (const float*)d_in[8];
  const float* Wo   = (const float*)d_in[9];
  const float* bo   = (const float*)d_in[10];
  const float* sink = (const float*)d_in[11];
  const int* slide  = (const int*)d_in[12];
  const int* winp   = (const int*)d_in[13];
  float* out = (float*)d_out;

  // Workspace (62.26 MB peak, proven):
  //   [0, 11.80M)       xb ; [0, 16.78M) ybuf (after xb/wkvT dead)
  //   [11.80M, 17.69M)  wkvT (dead after gemm1)
  //   [17.69M, 38.67M)  qkv
  //   [38.67M, 62.26M)  wqT -> woT (sequential reuse)
  char* ws = (char*)d_ws;
  u16* xb   = (u16*)(ws + 0);
  u16* ybuf = (u16*)(ws + 0);
  u16* wkvT = (u16*)(ws + 11796480);
  u16* qkv  = (u16*)(ws + 17694720);
  u16* wqT  = (u16*)(ws + 38666240);
  u16* woT  = (u16*)(ws + 38666240);

  // preps
  k_prep1<<<5760 + 11520, 256, 0, stream>>>(xb, x, wqT, Wq);
  k_prep2<<<1440 + 1440, 256, 0, stream>>>(wkvT, Wk, Wv);
  // Fused QKV projection + RoPE: M=2048, N=5120, BN=160 -> 8x32 = 256 WGs (exact fill)
  k_gx<160, 0, 1><<<256, 512, 0, stream>>>(xb, wqT, wkvT, bq, bk, bv, qkv, pos, 2048, 5120, 2880, 5120);
  // prep3: WoT
  k_prep3<<<11520, 256, 0, stream>>>(woT, Wo);
  // attention
  k_attn<<<1024, 256, 0, stream>>>(qkv, sink, ybuf, slide, winp);
  // output projection: M=2048, N=2880, BN=96 -> 8x30 = 240 WGs (single wave)
  k_gx<96, 1, 0><<<240, 512, 0, stream>>>(ybuf, woT, woT, bo, bo, bo, out, pos, 2048, 2880, 4096, 2880);
}

// Round 12
// 173.516 us; speedup vs baseline: 1.4863x; 1.0488x over previous
//
#include <hip/hip_runtime.h>

typedef unsigned short u16;
typedef __attribute__((ext_vector_type(8))) short bf16x8;
typedef __attribute__((ext_vector_type(4))) float f32x4;

#define MFMA16(a,b,c) __builtin_amdgcn_mfma_f32_16x16x32_bf16((a),(b),(c),0,0,0)

__device__ __forceinline__ float b2f(u16 u){
  unsigned v = ((unsigned)u) << 16; float f;
  __builtin_memcpy(&f, &v, 4); return f;
}
__device__ __forceinline__ u16 f2b(float f){
  unsigned v; __builtin_memcpy(&v, &f, 4);
  v += 0x7FFFu + ((v >> 16) & 1u);
  return (u16)(v >> 16);
}
__device__ __forceinline__ float scrub(float v, float lim){
  return fminf(fmaxf(v, -lim), lim);   // NaN-filtering clamp
}
__device__ __forceinline__ void gload16(const void* g, void* l){
  __builtin_amdgcn_global_load_lds(
      (const __attribute__((address_space(1))) unsigned int*)g,
      (__attribute__((address_space(3))) unsigned int*)l, 16, 0, 0);
}

// ---- convert+transpose tile helper: dst[c][r] = bf16(src[r][c]) ----
__device__ __forceinline__ void cvtT_tile(float (*tile)[33],
    u16* __restrict__ dst, const float* __restrict__ src,
    int rows, int cols, int bx, int by, int tid){
  int n0 = bx * 32, r0 = by * 32;
  int tx = tid & 31, ty = tid >> 5;
#pragma unroll
  for (int i = 0; i < 4; i++)
    tile[ty + i * 8][tx] = src[(size_t)(r0 + ty + i * 8) * cols + n0 + tx];
  __syncthreads();
#pragma unroll
  for (int i = 0; i < 4; i++)
    dst[(size_t)(n0 + ty + i * 8) * rows + r0 + tx] = f2b(tile[tx][ty + i * 8]);
}

// ---- prep1: x->bf16 (5760) + WqT (11520) + WkT (1440) + WvT (1440) ----
__global__ __launch_bounds__(256) void k_prep1(
    u16* __restrict__ xb, const float* __restrict__ x,
    u16* __restrict__ wqT, const float* __restrict__ Wq,
    u16* __restrict__ wkvT, const float* __restrict__ Wk,
    const float* __restrict__ Wv){
  __shared__ float tile[32][33];
  int b = blockIdx.x, tid = threadIdx.x;
  if (b < 5760){
    int i = b * 256 + tid;
    float4 v = ((const float4*)x)[i];
    u16 o[4] = { f2b(v.x), f2b(v.y), f2b(v.z), f2b(v.w) };
    *(uint2*)&xb[(size_t)i * 4] = *(const uint2*)o;
    return;
  }
  b -= 5760;
  if (b < 11520){ cvtT_tile(tile, wqT, Wq, 2880, 4096, b % 128, b / 128, tid); return; }
  b -= 11520;
  if (b < 1440){ cvtT_tile(tile, wkvT, Wk, 2880, 512, b % 16, b / 16, tid); return; }
  b -= 1440;
  cvtT_tile(tile, wkvT + (size_t)512 * 2880, Wv, 2880, 512, b % 16, b / 16, tid);
}

// ======== exact-fill GEMM: BM=256 x BN(160|96), BK=64, 512 thr (8 waves 4Mx2N) ====
// Proven 3-ring structure: reads buf t, stages buf t+2, ONE barrier +
// counted vmcnt per K-tile, 16B k-XOR swizzle (0 conflicts), setprio.
// mt-MAJOR block mapping (bid = mt*NTC + nt): contiguous grid/8 chunks share
// one A-panel -> A fetched once per XCD instead of 8x (FETCH 121->~45MB test).
template<int BN, int NTC, int F32OUT, int ROPE>
__global__ __launch_bounds__(512, 1) void k_gx(
    const u16* __restrict__ A, const u16* __restrict__ BT, const u16* __restrict__ BT2,
    const float* __restrict__ b0, const float* __restrict__ b1, const float* __restrict__ b2,
    void* __restrict__ C, const int* __restrict__ pos, int M, int N, int K, int ldc){
  constexpr int NF   = BN / 32;          // B frags per wave (per k-half)
  constexpr int FULL = (BN - 32) / 64;   // full 64-row B chunks
  constexpr int BUFE = 16384 + BN * 64;  // u16 elems per ring buf
  constexpr int VMW  = 4 + FULL;         // counted wait (min per-wave in-flight)
  __shared__ u16 lds[3][BUFE];           // A[256][64] @0, B[BN][64] @16384

  const int tid = threadIdx.x;
  const int w = tid >> 6, l = tid & 63;
  const int wm = w >> 1, wn = w & 1;     // 4 x 2 waves; per-wave 64 x BN/2
  const int lr = l & 15, lh = l >> 4;
  const int bid = blockIdx.x;
  const int mt = bid / NTC, nt = bid % NTC;  // mt-major: chunk shares A-panel
  const int m0 = mt << 8, n0 = nt * BN;

  const int srow = tid >> 3;             // 0..63
  const int skc  = (tid & 7) << 3;       // 0,8,..,56 elems
  const int ssw  = (srow & 7) << 3;      // stage-source k swizzle
  const int rsw  = (lr & 7) << 3;        // read-side k swizzle
  const int rrow = tid >> 3;             // rem-chunk row (tids<256 -> 0..31)

  f32x4 acc[4][NF];
#pragma unroll
  for (int mm = 0; mm < 4; mm++)
#pragma unroll
    for (int nn = 0; nn < NF; nn++){ acc[mm][nn][0]=0.f; acc[mm][nn][1]=0.f; acc[mm][nn][2]=0.f; acc[mm][nn][3]=0.f; }

#define STAGE_A(b, kt, c) \
  gload16(&A[(size_t)(m0 + (c)*64 + srow) * K + (kt) + (skc ^ ssw)], \
          (void*)&lds[b][((c)*64 + srow) * 64 + skc])
#define STAGE_BF(b, kt, c) { \
  int _r = n0 + (c)*64 + srow; \
  const u16* _bt = BT; if (ROPE && _r >= 4096){ _bt = BT2; _r -= 4096; } \
  gload16(&_bt[(size_t)_r * K + (kt) + (skc ^ ssw)], \
          (void*)&lds[b][16384 + ((c)*64 + srow) * 64 + skc]); }
#define STAGE_BR(b, kt) if (tid < 256){ \
  int _r = n0 + FULL*64 + rrow; \
  const u16* _bt = BT; if (ROPE && _r >= 4096){ _bt = BT2; _r -= 4096; } \
  gload16(&_bt[(size_t)_r * K + (kt) + (skc ^ ((rrow & 7) << 3))], \
          (void*)&lds[b][16384 + (FULL*64 + rrow) * 64 + skc]); }

#define RD_A(dst, b, mm, kk) dst = *(const bf16x8*)&lds[b][((wm<<6) + ((mm)<<4) + lr) * 64 + ((((kk)<<5) + (lh<<3)) ^ rsw)]
#define RD_B(dst, b, nn, kk) dst = *(const bf16x8*)&lds[b][16384 + (wn*(BN/2) + (nn)*16 + lr) * 64 + ((((kk)<<5) + (lh<<3)) ^ rsw)]

  const int NT = K >> 6;
  // prologue: stage tiles 0,1 into bufs 0,1
#pragma unroll
  for (int tt = 0; tt < 2; ++tt){
    int kt = tt << 6;
#pragma unroll
    for (int c = 0; c < 4; ++c) STAGE_A(tt, kt, c);
#pragma unroll
    for (int c = 0; c < FULL; ++c) STAGE_BF(tt, kt, c);
    STAGE_BR(tt, kt);
  }
  asm volatile("s_waitcnt vmcnt(%0)" :: "i"(VMW) : "memory");   // tile 0 complete
  __builtin_amdgcn_s_barrier();

  int cb = 0;
  for (int t = 0; t < NT; ++t){
    int sb = cb + 2; if (sb >= 3) sb -= 3;
    const int kt2 = (t + 2) << 6;
    const bool ds = (t + 2) < NT;

    bf16x8 bf[NF][2];
#pragma unroll
    for (int nn = 0; nn < NF; nn++){ RD_B(bf[nn][0], cb, nn, 0); RD_B(bf[nn][1], cb, nn, 1); }

#pragma unroll
    for (int mm = 0; mm < 4; mm++){
      bf16x8 a0, a1;
      RD_A(a0, cb, mm, 0); RD_A(a1, cb, mm, 1);
      if (ds){
        STAGE_A(sb, kt2, mm);
        if (mm < FULL) STAGE_BF(sb, kt2, mm);
        if (mm == 2) STAGE_BR(sb, kt2);
      }
      __builtin_amdgcn_s_setprio(1);
#pragma unroll
      for (int nn = 0; nn < NF; nn++) acc[mm][nn] = MFMA16(a0, bf[nn][0], acc[mm][nn]);
#pragma unroll
      for (int nn = 0; nn < NF; nn++) acc[mm][nn] = MFMA16(a1, bf[nn][1], acc[mm][nn]);
      __builtin_amdgcn_s_setprio(0);
    }

    if (ds) asm volatile("s_waitcnt vmcnt(%0)" :: "i"(VMW) : "memory");
    else    asm volatile("s_waitcnt vmcnt(0)" ::: "memory");
    __builtin_amdgcn_s_barrier();
    cb += 1; if (cb >= 3) cb -= 3;
  }

  // ---- epilogue ----
#pragma unroll
  for (int mm = 0; mm < 4; mm++){
    int grow = m0 + (wm << 6) + (mm << 4) + (lh << 2);
#pragma unroll
    for (int nn = 0; nn < NF; nn++){
      int gcol = n0 + wn * (BN / 2) + nn * 16 + lr;
      float bs;
      if (ROPE) bs = (gcol < 4096) ? b0[gcol] : ((gcol < 4608) ? b1[gcol - 4096] : b2[gcol - 4608]);
      else      bs = b0[gcol];
      if (ROPE && gcol < 4608){
        int ii = (gcol & 63) >> 1;
        float inv = exp2f(-0.53733146f * (float)ii);
        float sgn = (lr & 1) ? 1.f : -1.f;
#pragma unroll
        for (int r = 0; r < 4; r++){
          float v = acc[mm][nn][r] + bs;
          float ang = (float)pos[grow + r] * 0.03125f * inv;
          float s, c; __sincosf(ang, &s, &c);
          float p = __shfl_xor(v, 1);
          v = v * c + p * sgn * s;
          ((u16*)C)[(size_t)(grow + r) * ldc + gcol] = f2b(scrub(v, 1e9f));
        }
      } else {
#pragma unroll
        for (int r = 0; r < 4; r++){
          float v = scrub(acc[mm][nn][r] + bs, 1e9f);
          size_t off = (size_t)(grow + r) * ldc + gcol;
          if (F32OUT) ((float*)C)[off] = v;
          else        ((u16*)C)[off]   = f2b(v);
        }
      }
    }
  }
#undef STAGE_A
#undef STAGE_BF
#undef STAGE_BR
#undef RD_A
#undef RD_B
}

// ---------------- attention + WoT transpose (fat kernel) ----------------
// blocks 0..1023: attention (verified structure). blocks 1024..12543: WoT.
__global__ __launch_bounds__(256) void k_attn_prep(
    const u16* __restrict__ qkv, const float* __restrict__ sink,
    u16* __restrict__ y, const int* __restrict__ slide_p,
    const int* __restrict__ win_p,
    u16* __restrict__ woT, const float* __restrict__ Wo){
  __shared__ char smem[36864];

  if (blockIdx.x >= 1024){
    int b = blockIdx.x - 1024;
    float (*tile)[33] = (float(*)[33])smem;
    cvtT_tile(tile, woT, Wo, 4096, 2880, b % 90, b / 90, threadIdx.x);
    return;
  }

  u16 (*Ks)[72]       = (u16(*)[72])smem;              //  9216 B
  u16 (*VTs)[72]      = (u16(*)[72])(smem + 9216);     //  9216 B
  u16 (*Plds)[32][72] = (u16(*)[32][72])(smem + 18432);// 18432 B

  int bid = blockIdx.x;
  int qt = bid & 7, h = (bid >> 3) & 63, b = bid >> 9;
  int t0 = qt << 7;
  int g = h >> 3;
  int kcol = 4096 + g * 64, vcol = 4608 + g * 64;
  int tid = threadIdx.x, w = tid >> 6, l = tid & 63;
  int lr = l & 15, lh = l >> 4;
  int win = (*slide_p) ? (*win_p) : (1 << 30);
  int tq0 = t0 + w * 32;

  bf16x8 qf[2][2];
#pragma unroll
  for (int m = 0; m < 2; m++)
#pragma unroll
    for (int kk = 0; kk < 2; kk++){
      int q = tq0 + m * 16 + lr;
      qf[m][kk] = *(const bf16x8*)&qkv[(size_t)(b * 1024 + q) * 5120 + h * 64 + kk * 32 + lh * 8];
    }

  float run_max[2] = {-1e30f, -1e30f};
  float run_sum[2] = {0.f, 0.f};
  f32x4 acc_o[4][2];
#pragma unroll
  for (int dt = 0; dt < 4; dt++)
#pragma unroll
    for (int m = 0; m < 2; m++){ acc_o[dt][m][0]=0.f; acc_o[dt][m][1]=0.f; acc_o[dt][m][2]=0.f; acc_o[dt][m][3]=0.f; }

  for (int c = 0; c < 4; c++){
    int key0 = t0 - 128 + c * 64;
#pragma unroll
    for (int it = 0; it < 2; ++it){
      int idx = it * 256 + tid;
      int key = idx >> 3, dd = (idx & 7) << 3;
      int gk = key0 + key;
      uint4 kq = make_uint4(0, 0, 0, 0);
      uint4 vq = make_uint4(0, 0, 0, 0);
      if (gk >= 0){
        size_t rb = (size_t)(b * 1024 + gk) * 5120;
        kq = *(const uint4*)&qkv[rb + kcol + dd];
        vq = *(const uint4*)&qkv[rb + vcol + dd];
      }
      *(uint4*)&Ks[key][dd] = kq;
      const u16* tv = (const u16*)&vq;
#pragma unroll
      for (int j = 0; j < 8; j++) VTs[dd + j][key] = tv[j];
    }
    __syncthreads();

    bool rel = (key0 + 63 >= tq0 - (win - 1)) && (key0 <= tq0 + 31);
    if (rel){
      f32x4 sacc[2][4];
#pragma unroll
      for (int m = 0; m < 2; m++)
#pragma unroll
        for (int n = 0; n < 4; n++){ sacc[m][n][0]=0.f; sacc[m][n][1]=0.f; sacc[m][n][2]=0.f; sacc[m][n][3]=0.f; }
#pragma unroll
      for (int kk = 0; kk < 2; kk++){
#pragma unroll
        for (int n = 0; n < 4; n++){
          bf16x8 kf = *(const bf16x8*)&Ks[n * 16 + lr][kk * 32 + lh * 8];
          sacc[0][n] = MFMA16(kf, qf[0][kk], sacc[0][n]);
          sacc[1][n] = MFMA16(kf, qf[1][kk], sacc[1][n]);
        }
      }
#pragma unroll
      for (int m = 0; m < 2; m++){
        int qrow = tq0 + m * 16 + lr;
        float cmax = -INFINITY;
#pragma unroll
        for (int n = 0; n < 4; n++)
#pragma unroll
          for (int r = 0; r < 4; r++){
            int key = key0 + n * 16 + lh * 4 + r;
            float s = scrub(sacc[m][n][r] * 0.125f, 1e30f);
            bool valid = (key >= 0) && (key <= qrow) && (qrow - key < win);
            s = valid ? s : -INFINITY;
            sacc[m][n][r] = s;
            cmax = fmaxf(cmax, s);
          }
        cmax = fmaxf(cmax, __shfl_xor(cmax, 16));
        cmax = fmaxf(cmax, __shfl_xor(cmax, 32));
        float mnew = fmaxf(run_max[m], cmax);
        float corr = __expf(run_max[m] - mnew);
        run_max[m] = mnew;
        float rsum = 0.f;
#pragma unroll
        for (int n = 0; n < 4; n++)
#pragma unroll
          for (int r = 0; r < 4; r++){
            float p = __expf(sacc[m][n][r] - mnew);
            sacc[m][n][r] = p;
            rsum += p;
          }
        rsum += __shfl_xor(rsum, 16);
        rsum += __shfl_xor(rsum, 32);
        run_sum[m] = run_sum[m] * corr + rsum;
#pragma unroll
        for (int dt = 0; dt < 4; dt++) acc_o[dt][m] *= corr;
#pragma unroll
        for (int n = 0; n < 4; n++)
#pragma unroll
          for (int r = 0; r < 4; r++)
            Plds[w][m * 16 + lr][n * 16 + lh * 4 + r] = f2b(sacc[m][n][r]);
      }
#pragma unroll
      for (int ks = 0; ks < 2; ks++){
        bf16x8 pb[2];
#pragma unroll
        for (int m = 0; m < 2; m++)
          pb[m] = *(const bf16x8*)&Plds[w][m * 16 + lr][ks * 32 + lh * 8];
#pragma unroll
        for (int dt = 0; dt < 4; dt++){
          bf16x8 vf = *(const bf16x8*)&VTs[dt * 16 + lr][ks * 32 + lh * 8];
          acc_o[dt][0] = MFMA16(vf, pb[0], acc_o[dt][0]);
          acc_o[dt][1] = MFMA16(vf, pb[1], acc_o[dt][1]);
        }
      }
    }
    __syncthreads();
  }

  float sk = sink[h];
  float osc[2];
#pragma unroll
  for (int m = 0; m < 2; m++){
    float Mf = fmaxf(run_max[m], sk);
    float t = __expf(run_max[m] - Mf);
    float denom = run_sum[m] * t + __expf(sk - Mf);
    osc[m] = t / denom;
  }
#pragma unroll
  for (int dt = 0; dt < 4; dt++)
#pragma unroll
    for (int m = 0; m < 2; m++)
#pragma unroll
      for (int r = 0; r < 4; r++){
        int d = dt * 16 + lh * 4 + r;
        int q = tq0 + m * 16 + lr;
        y[(size_t)(b * 1024 + q) * 4096 + h * 64 + d] = f2b(scrub(acc_o[dt][m][r] * osc[m], 1e9f));
      }
}

// ---------------- host ----------------
extern "C" void kernel_launch(void* const* d_in, const int* in_sizes, int n_in,
                              void* d_out, int out_size, void* d_ws, size_t ws_size,
                              hipStream_t stream){
  const float* x    = (const float*)d_in[0];
  const int*   pos  = (const int*)d_in[1];
  const float* Wq   = (const float*)d_in[3];
  const float* bq   = (const float*)d_in[4];
  const float* Wk   = (const float*)d_in[5];
  const float* bk   = (const float*)d_in[6];
  const float* Wv   = (const float*)d_in[7];
  const float* bv   = (const float*)d_in[8];
  const float* Wo   = (const float*)d_in[9];
  const float* bo   = (const float*)d_in[10];
  const float* sink = (const float*)d_in[11];
  const int* slide  = (const int*)d_in[12];
  const int* winp   = (const int*)d_in[13];
  float* out = (float*)d_out;

  // Workspace (62.26 MB peak, proven):
  //   [0, 11.80M)       xb ; [0, 16.78M) ybuf (after xb/wkvT dead)
  //   [11.80M, 17.69M)  wkvT (dead after gemm1)
  //   [17.69M, 38.67M)  qkv
  //   [38.67M, 62.26M)  wqT -> woT (sequential reuse)
  char* ws = (char*)d_ws;
  u16* xb   = (u16*)(ws + 0);
  u16* ybuf = (u16*)(ws + 0);
  u16* wkvT = (u16*)(ws + 11796480);
  u16* qkv  = (u16*)(ws + 17694720);
  u16* wqT  = (u16*)(ws + 38666240);
  u16* woT  = (u16*)(ws + 38666240);

  // prep1: x->bf16 + WqT + WkT + WvT (single launch)
  k_prep1<<<5760 + 11520 + 2880, 256, 0, stream>>>(xb, x, wqT, Wq, wkvT, Wk, Wv);
  // Fused QKV projection + RoPE: BN=160 -> 8 mt x 32 nt = 256 WGs, mt-major
  k_gx<160, 32, 0, 1><<<256, 512, 0, stream>>>(xb, wqT, wkvT, bq, bk, bv, qkv, pos, 2048, 5120, 2880, 5120);
  // attention (1024) + WoT transpose (11520) fat kernel
  k_attn_prep<<<1024 + 11520, 256, 0, stream>>>(qkv, sink, ybuf, slide, winp, woT, Wo);
  // output projection: BN=96 -> 8 mt x 30 nt = 240 WGs, mt-major (fp32 out)
  k_gx<96, 30, 1, 0><<<240, 512, 0, stream>>>(ybuf, woT, woT, bo, bo, bo, out, pos, 2048, 2880, 4096, 2880);
}